// Round 14
// baseline (142.241 us; speedup 1.0000x reference)
//
#include <hip/hip_runtime.h>
#include <hip/hip_bf16.h>

#define DMODEL 512
#define NHEAD  8
#define DKH    64
#define SEQ    2048
#define NB     4
#define LOG2E  1.44269504088896f

typedef float f32x4 __attribute__((ext_vector_type(4)));
typedef float f32x16 __attribute__((ext_vector_type(16)));
typedef short bf16x8 __attribute__((ext_vector_type(8)));

__device__ __forceinline__ unsigned short f2bf(float x) {
    unsigned int u = __float_as_uint(x);
    u += 0x7fffu + ((u >> 16) & 1u);
    return (unsigned short)(u >> 16);
}

__device__ __forceinline__ void gload16(const void* g, void* l) {
    __builtin_amdgcn_global_load_lds(
        (const __attribute__((address_space(1))) unsigned int*)g,
        (__attribute__((address_space(3))) unsigned int*)l, 16, 0, 0);
}

__device__ __forceinline__ unsigned int cvtpk(float lo, float hi) {
    // no builtin on gfx950 (learn_hip m240) — inline asm
    unsigned int r;
    asm("v_cvt_pk_bf16_f32 %0, %1, %2" : "=v"(r) : "v"(lo), "v"(hi));
    return r;
}

// ---------------------------------------------------------------------------
// prep_wcvt: W f32->bf16 only (6MB traffic, ~2us). Mask pack moved into the
// QKV-GEMM launch so its 67MB read overlaps gemm compute.
// ---------------------------------------------------------------------------
struct WcvtArgs { const float* src[4]; unsigned short* dst[4]; };

__global__ __launch_bounds__(256) void prep_wcvt(WcvtArgs a)
{
    const int seg = blockIdx.x >> 7, base = blockIdx.x & 127;
    const int i = (base * 256 + threadIdx.x) * 8;
    const float* s = a.src[seg];
    const float4 v0 = *reinterpret_cast<const float4*>(s + i);
    const float4 v1 = *reinterpret_cast<const float4*>(s + i + 4);
    ushort4 h0, h1;
    h0.x = f2bf(v0.x); h0.y = f2bf(v0.y); h0.z = f2bf(v0.z); h0.w = f2bf(v0.w);
    h1.x = f2bf(v1.x); h1.y = f2bf(v1.y); h1.z = f2bf(v1.z); h1.w = f2bf(v1.w);
    *reinterpret_cast<ushort4*>(a.dst[seg] + i)     = h0;
    *reinterpret_cast<ushort4*>(a.dst[seg] + i + 4) = h1;
}

// ---------------------------------------------------------------------------
// Shared GEMM body (proven round-13 code, bm/bn as args). AF32=true: A is
// f32, reg-staged with v_cvt_pk_bf16_f32 + swizzled ds_write_b128 (invariant
// matches gload16 path: LDS[row, unit w^(row&7)] = A[row, unit w]); next
// tile's f32 loads prefetched under compute. AF32=false: gload16 path.
// ---------------------------------------------------------------------------
struct GemmSet {
    const void* A; const unsigned short* W; const float* bias;
    unsigned short* outb; float* outf; float scale; int mode;
};
struct Gemm3 { GemmSet s[3]; };

template<int BM, bool AF32>
__device__ __forceinline__ void gemm_body(const GemmSet& gs, int bm, int bn,
                                          unsigned short* As, unsigned short* Bs)
{
    constexpr int NJ = (BM == 128) ? 4 : 2;
    const int tid = threadIdx.x, lane = tid & 63, wv = tid >> 6;
    const int g = lane >> 4, lr = lane & 15;
    const int wm = (BM == 128) ? (wv & 1) * 64 : 0;
    const int wn = (BM == 128) ? (wv >> 1) * 64 : wv * 32;
    const int srow = lane >> 3;
    const int scol = 8 * ((lane & 7) ^ srow);

    // AF32 staging geometry: thread -> (row, 64-f32 half), 4x 16B units
    const int arow  = tid >> 1;      // 0..127
    const int ahalf = tid & 1;       // 0..1

    f32x4 acc[4][NJ] = {};
    float4 ra[8];

    if constexpr (AF32) {
        const float* Af = (const float*)gs.A;
        #pragma unroll
        for (int j = 0; j < 4; ++j) {
            const size_t gb = (size_t)(bm + arow) * DMODEL + ahalf * 32 + j * 8;
            ra[2*j]   = *reinterpret_cast<const float4*>(&Af[gb]);
            ra[2*j+1] = *reinterpret_cast<const float4*>(&Af[gb + 4]);
        }
    }

    #pragma unroll
    for (int kt = 0; kt < DMODEL; kt += 64) {
        __syncthreads();
        if constexpr (AF32) {
            #pragma unroll
            for (int j = 0; j < 4; ++j) {
                unsigned int w0 = cvtpk(ra[2*j].x,   ra[2*j].y);
                unsigned int w1 = cvtpk(ra[2*j].z,   ra[2*j].w);
                unsigned int w2 = cvtpk(ra[2*j+1].x, ra[2*j+1].y);
                unsigned int w3 = cvtpk(ra[2*j+1].z, ra[2*j+1].w);
                uint4 pkd; pkd.x = w0; pkd.y = w1; pkd.z = w2; pkd.w = w3;
                const int boff = (arow * 128 + ahalf * 64 + j * 16) ^ ((arow & 7) << 4);
                *reinterpret_cast<uint4*>((char*)As + boff) = pkd;   // ds_write_b128
            }
        } else {
            #pragma unroll
            for (int i = 0; i < BM / 32; ++i) {
                const int ch = i * 4 + wv;
                const int row = ch * 8 + srow;
                gload16(&((const unsigned short*)gs.A)[(size_t)(bm + row) * DMODEL + kt + scol],
                        &As[ch * 512 + lane * 8]);
            }
        }
        #pragma unroll
        for (int i = 0; i < 4; ++i) {
            const int ch = i * 4 + wv;
            const int row = ch * 8 + srow;
            gload16(&gs.W[(size_t)(bn + row) * DMODEL + kt + scol], &Bs[ch * 512 + lane * 8]);
        }
        if constexpr (AF32) {
            if (kt + 64 < DMODEL) {
                const float* Af = (const float*)gs.A;
                #pragma unroll
                for (int j = 0; j < 4; ++j) {
                    const size_t gb = (size_t)(bm + arow) * DMODEL + kt + 64 + ahalf * 32 + j * 8;
                    ra[2*j]   = *reinterpret_cast<const float4*>(&Af[gb]);
                    ra[2*j+1] = *reinterpret_cast<const float4*>(&Af[gb + 4]);
                }
            }
        }
        __syncthreads();

        #pragma unroll
        for (int kk = 0; kk < 2; ++kk) {
            bf16x8 af[4], bfr[NJ];
            #pragma unroll
            for (int x = 0; x < 4; ++x) {
                const int ra_ = wm + x * 16 + lr;
                af[x] = *reinterpret_cast<const bf16x8*>(
                    (const char*)As + ((ra_ * 128 + kk * 64 + g * 16) ^ ((ra_ & 7) << 4)));
            }
            #pragma unroll
            for (int y = 0; y < NJ; ++y) {
                const int rb = wn + y * 16 + lr;
                bfr[y] = *reinterpret_cast<const bf16x8*>(
                    (const char*)Bs + ((rb * 128 + kk * 64 + g * 16) ^ ((rb & 7) << 4)));
            }
            __builtin_amdgcn_s_setprio(1);
            #pragma unroll
            for (int mi = 0; mi < 4; ++mi)
                #pragma unroll
                for (int nj = 0; nj < NJ; ++nj)
                    acc[mi][nj] = __builtin_amdgcn_mfma_f32_16x16x32_bf16(af[mi], bfr[nj], acc[mi][nj], 0, 0, 0);
            __builtin_amdgcn_s_setprio(0);
        }
    }

    const int mode = gs.mode;
    #pragma unroll
    for (int mi = 0; mi < 4; ++mi) {
        #pragma unroll
        for (int nj = 0; nj < NJ; ++nj) {
            const int col  = bn + wn + nj * 16 + lr;
            const int row0 = bm + wm + mi * 16 + g * 4;
            const float bv = gs.bias[col];
            if (mode == 2) {
                const int bb = row0 >> 11, ss = row0 & (SEQ - 1);
                const int hh = col >> 6,  dd = col & 63;
                ushort4 pk;
                pk.x = f2bf(acc[mi][nj][0] + bv);
                pk.y = f2bf(acc[mi][nj][1] + bv);
                pk.z = f2bf(acc[mi][nj][2] + bv);
                pk.w = f2bf(acc[mi][nj][3] + bv);
                *reinterpret_cast<ushort4*>(&gs.outb[((size_t)((bb * NHEAD + hh) * DKH + dd)) * SEQ + ss]) = pk;
            } else if (mode == 3) {
                #pragma unroll
                for (int r = 0; r < 4; ++r)
                    gs.outf[(size_t)(row0 + r) * DMODEL + col] = acc[mi][nj][r] + bv;
            } else {
                #pragma unroll
                for (int r = 0; r < 4; ++r)
                    gs.outb[(size_t)(row0 + r) * DMODEL + col] = f2bf((acc[mi][nj][r] + bv) * gs.scale);
            }
        }
    }
}

// ---------------------------------------------------------------------------
// Fused QKV-GEMM + mask bit-pack. Blocks 0..767: z-major flattened gemm
// (z = bx>>8; bm = ((bx&255)>>2)*128; bn = (bx&3)*128). Blocks 768..1791:
// pack (verbatim round-13 logic). Pack is memory-bound and independent of
// the gemm -> overlaps under the gemm's compute instead of serializing.
// ---------------------------------------------------------------------------
#define GEMM_BLOCKS 768
#define PACK_BLOCKS 1024
struct FusedArgs {
    GemmSet s[3];
    const unsigned char* mask; unsigned long long* bits;
};

__global__ __launch_bounds__(256) void gemm_qkv_pack(FusedArgs a)
{
    __shared__ unsigned short As[128 * 64];
    __shared__ unsigned short Bs[128 * 64];
    const int bx = blockIdx.x;
    if (bx < GEMM_BLOCKS) {
        const int gz = bx >> 8, rem = bx & 255;
        gemm_body<128, true>(a.s[gz], (rem >> 2) * 128, (rem & 3) * 128, As, Bs);
    } else {
        __shared__ int anyb;
        if (threadIdx.x == 0) anyb = 0;
        __syncthreads();
        const uint4 dv = *reinterpret_cast<const uint4*>(a.mask + threadIdx.x * 16);
        if ((dv.x | dv.y | dv.z | dv.w) & 0xFFFFFF00u) atomicOr(&anyb, 1);
        __syncthreads();
        const int bytemode = anyb;

        const int w = (bx - GEMM_BLOCKS) * 256 + threadIdx.x;   // 0..262143
        const int b = w >> 16, kt = (w >> 11) & 31, row = w & 2047;
        const size_t eoff = ((size_t)(b * SEQ + row)) * SEQ + kt * 64;
        unsigned long long word = 0;
        if (bytemode) {
            const unsigned char* mp = a.mask + eoff;
            #pragma unroll
            for (int c = 0; c < 4; ++c) {
                const uint4 v = *reinterpret_cast<const uint4*>(mp + c * 16);
                const unsigned int n0 = (v.x | (v.x >> 7) | (v.x >> 14) | (v.x >> 21)) & 0xFu;
                const unsigned int n1 = (v.y | (v.y >> 7) | (v.y >> 14) | (v.y >> 21)) & 0xFu;
                const unsigned int n2 = (v.z | (v.z >> 7) | (v.z >> 14) | (v.z >> 21)) & 0xFu;
                const unsigned int n3 = (v.w | (v.w >> 7) | (v.w >> 14) | (v.w >> 21)) & 0xFu;
                const unsigned int ch = n0 | (n1 << 4) | (n2 << 8) | (n3 << 12);
                word |= (unsigned long long)ch << (16 * c);
            }
        } else {
            const unsigned int* mp = (const unsigned int*)a.mask + eoff;
            #pragma unroll
            for (int c = 0; c < 16; ++c) {
                const uint4 v = *reinterpret_cast<const uint4*>(mp + c * 4);
                const unsigned int nb = (v.x | (v.y << 1) | (v.z << 2) | (v.w << 3)) & 0xFu;
                word |= (unsigned long long)nb << (4 * c);
            }
        }
        a.bits[w] = word;
    }
}

// ---------------------------------------------------------------------------
// O-projection GEMM (BM=64, bf16 A via gload16) — proven path.
// ---------------------------------------------------------------------------
__global__ __launch_bounds__(256) void gemm_o(Gemm3 G)
{
    __shared__ unsigned short As[64 * 64];
    __shared__ unsigned short Bs[128 * 64];
    gemm_body<64, false>(G.s[0], blockIdx.x * 64, blockIdx.y * 128, As, Bs);
}

// ---------------------------------------------------------------------------
// Flash attention — round-13 verbatim (4 waves, KVBLK=128, counted-vmcnt raw
// barriers, 2-deep prefetch, exp2f [__builtin_amdgcn_exp2f is BANNED —
// failed rounds 7 & 12 with absmax ~0.74]).
// ---------------------------------------------------------------------------
__global__ __launch_bounds__(256) void attn_fwd(
    const unsigned short* __restrict__ Q,
    const unsigned short* __restrict__ K,
    const unsigned short* __restrict__ Vt,
    const unsigned long long* __restrict__ bits,
    unsigned short* __restrict__ X)
{
    __shared__ unsigned short Ks[2][2][64 * 64];   // [buf][half][64 rows x 128B]
    __shared__ unsigned short Vs[2][2][64 * 64];

    const int tid = threadIdx.x, lane = tid & 63, wv = tid >> 6;
    const int lr32 = lane & 31, hi = lane >> 5;
    const int bid = blockIdx.x;
    const int wg  = (bid & 7) * 64 + (bid >> 3);
    const int qb = wg & 15, h = (wg >> 4) & 7, b = wg >> 7;
    const int q0 = qb * 128, qw = q0 + wv * 32;

    const unsigned short* Kbh = K  + (size_t)b * SEQ * DMODEL + h * DKH;
    const unsigned short* Vbh = Vt + (size_t)(b * NHEAD + h) * DKH * SEQ;
    const unsigned long long* bitsb = bits + (size_t)b * 32 * SEQ + qw + lr32;

    bf16x8 qf[4];
    #pragma unroll
    for (int kd = 0; kd < 4; ++kd)
        qf[kd] = *reinterpret_cast<const bf16x8*>(
            &Q[(size_t)(b * SEQ + qw + lr32) * DMODEL + h * DKH + kd * 16 + hi * 8]);

    const int srow = lane >> 3;
    const int scol = 8 * ((lane & 7) ^ srow);

    auto stage = [&](int buf, int c) {
        #pragma unroll
        for (int i = 0; i < 4; ++i) {
            const int ch   = i * 4 + wv;
            const int half = ch >> 3;
            const int chh  = ch & 7;
            const int row  = chh * 8 + srow;
            const int kt   = c * 128 + half * 64;
            gload16(&Kbh[(size_t)(kt + row) * DMODEL + scol], &Ks[buf][half][chh * 512 + lane * 8]);
            gload16(&Vbh[(size_t)row * SEQ + kt + scol],      &Vs[buf][half][chh * 512 + lane * 8]);
        }
    };

    union { unsigned int u[4]; bf16x8 v; } onesu;
    onesu.u[0] = onesu.u[1] = onesu.u[2] = onesu.u[3] = 0x3F803F80u;
    const bf16x8 ones = onesu.v;

    f32x16 o0 = {}, o1 = {}, o_sum = {};

    stage(0, 0);
    stage(1, 1);   // 2-deep prefetch

    for (int t = 0; t < 16; ++t) {
        const int cur = t & 1;

        if (t < 15) asm volatile("s_waitcnt vmcnt(8)" ::: "memory");
        else        asm volatile("s_waitcnt vmcnt(0)" ::: "memory");
        __builtin_amdgcn_sched_barrier(0);
        __builtin_amdgcn_s_barrier();

        const unsigned long long mwA = bitsb[(size_t)(2 * t)     * SEQ];
        const unsigned long long mwB = bitsb[(size_t)(2 * t + 1) * SEQ];

        f32x16 sA0 = {}, sA1 = {}, sB0 = {}, sB1 = {};
        __builtin_amdgcn_s_setprio(1);
        #pragma unroll
        for (int kd = 0; kd < 4; ++kd) {
            const int cb = kd * 32 + hi * 16;
            const int r0 = lr32, r1 = 32 + lr32;
            const bf16x8 kfA0 = *reinterpret_cast<const bf16x8*>(
                (const char*)Ks[cur][0] + ((r0 * 128 + cb) ^ ((r0 & 7) << 4)));
            const bf16x8 kfA1 = *reinterpret_cast<const bf16x8*>(
                (const char*)Ks[cur][0] + ((r1 * 128 + cb) ^ ((r1 & 7) << 4)));
            const bf16x8 kfB0 = *reinterpret_cast<const bf16x8*>(
                (const char*)Ks[cur][1] + ((r0 * 128 + cb) ^ ((r0 & 7) << 4)));
            const bf16x8 kfB1 = *reinterpret_cast<const bf16x8*>(
                (const char*)Ks[cur][1] + ((r1 * 128 + cb) ^ ((r1 & 7) << 4)));
            sA0 = __builtin_amdgcn_mfma_f32_32x32x16_bf16(kfA0, qf[kd], sA0, 0, 0, 0);
            sA1 = __builtin_amdgcn_mfma_f32_32x32x16_bf16(kfA1, qf[kd], sA1, 0, 0, 0);
            sB0 = __builtin_amdgcn_mfma_f32_32x32x16_bf16(kfB0, qf[kd], sB0, 0, 0, 0);
            sB1 = __builtin_amdgcn_mfma_f32_32x32x16_bf16(kfB1, qf[kd], sB1, 0, 0, 0);
        }
        __builtin_amdgcn_s_setprio(0);

        auto subtile = [&](const f32x16& s0, const f32x16& s1,
                           unsigned long long mw, int sub) {
            const unsigned long long msh = mw >> (4 * hi);
            const unsigned int mlo = (unsigned int)msh;
            const unsigned int mhi = (unsigned int)(msh >> 32);
            unsigned int pk[8][2];
            #pragma unroll
            for (int kj = 0; kj < 2; ++kj) {
                const unsigned int msel = kj ? mhi : mlo;
                #pragma unroll
                for (int o2 = 0; o2 < 4; ++o2) {
                    float p[4];
                    #pragma unroll
                    for (int r = 0; r < 4; ++r) {
                        const int bitp = o2 * 8 + r;
                        const float mf = (float)(msel & (1u << bitp));    // 0 or 2^bitp exact
                        const float coef = -1024.f / (float)(1u << bitp); // exact
                        const float sv = kj ? s1[o2 * 4 + r] : s0[o2 * 4 + r];
                        p[r] = exp2f(__builtin_fmaf(mf, coef, sv));       // masked: exp2(s-1024)=0
                    }
                    pk[kj * 4 + o2][0] = cvtpk(p[0], p[1]);
                    pk[kj * 4 + o2][1] = cvtpk(p[2], p[3]);
                }
            }
            #pragma unroll
            for (int kk = 0; kk < 4; ++kk) {
                unsigned int a0 = pk[2 * kk][0], b0 = pk[2 * kk + 1][0];
                unsigned int a1 = pk[2 * kk][1], b1 = pk[2 * kk + 1][1];
                asm("v_permlane32_swap_b32 %0, %1" : "+v"(a0), "+v"(b0));
                asm("v_permlane32_swap_b32 %0, %1" : "+v"(a1), "+v"(b1));
                union { unsigned int u[4]; bf16x8 v; } fr;
                fr.u[0] = a0; fr.u[1] = a1; fr.u[2] = b0; fr.u[3] = b1;
                const int cb = kk * 32 + hi * 16;
                const int d0 = lr32, d1 = 32 + lr32;
                const bf16x8 vf0 = *reinterpret_cast<const bf16x8*>(
                    (const char*)Vs[cur][sub] + ((d0 * 128 + cb) ^ ((d0 & 7) << 4)));
                const bf16x8 vf1 = *reinterpret_cast<const bf16x8*>(
                    (const char*)Vs[cur][sub] + ((d1 * 128 + cb) ^ ((d1 & 7) << 4)));
                __builtin_amdgcn_s_setprio(1);
                o0    = __builtin_amdgcn_mfma_f32_32x32x16_bf16(fr.v, vf0, o0, 0, 0, 0);
                o1    = __builtin_amdgcn_mfma_f32_32x32x16_bf16(fr.v, vf1, o1, 0, 0, 0);
                o_sum = __builtin_amdgcn_mfma_f32_32x32x16_bf16(fr.v, ones, o_sum, 0, 0, 0);
                __builtin_amdgcn_s_setprio(0);
            }
        };
        subtile(sA0, sA1, mwA, 0);
        subtile(sB0, sB1, mwB, 1);

        __builtin_amdgcn_s_barrier();
        if (t + 2 <= 15) stage(cur, t + 2);
    }

    #pragma unroll
    for (int r = 0; r < 16; ++r) {
        const int qr = (r & 3) + 8 * (r >> 2) + 4 * hi;
        const float rv = 1.f / o_sum[r];
        const size_t rowoff = (size_t)(b * SEQ + qw + qr) * DMODEL + h * DKH + lr32;
        X[rowoff]      = f2bf(o0[r] * rv);
        X[rowoff + 32] = f2bf(o1[r] * rv);
    }
}

extern "C" void kernel_launch(void* const* d_in, const int* in_sizes, int n_in,
                              void* d_out, int out_size, void* d_ws, size_t ws_size,
                              hipStream_t stream)
{
    const float* query = (const float*)d_in[0];
    const float* key   = (const float*)d_in[1];
    const float* value = (const float*)d_in[2];
    const unsigned char* mask = (const unsigned char*)d_in[3];
    const float* Wq = (const float*)d_in[4];
    const float* bq = (const float*)d_in[5];
    const float* Wk = (const float*)d_in[6];
    const float* bk = (const float*)d_in[7];
    const float* Wv = (const float*)d_in[8];
    const float* bv = (const float*)d_in[9];
    const float* Wo = (const float*)d_in[10];
    const float* bo = (const float*)d_in[11];

    const size_t E = (size_t)(NB * SEQ) * DMODEL;          // 4,194,304
    const size_t WE = (size_t)DMODEL * DMODEL;             // 262,144
    unsigned short* Xp  = (unsigned short*)d_ws;
    unsigned short* Qp  = Xp + E;
    unsigned short* Kp  = Qp + E;
    unsigned short* Vtp = Kp + E;
    unsigned short* Wqb = Vtp + E;
    unsigned short* Wkb = Wqb + WE;
    unsigned short* Wvb = Wkb + WE;
    unsigned short* Wob = Wvb + WE;
    unsigned long long* bits = (unsigned long long*)(Wob + WE);

    WcvtArgs wa;
    wa.src[0] = Wq; wa.src[1] = Wk; wa.src[2] = Wv; wa.src[3] = Wo;
    wa.dst[0] = Wqb; wa.dst[1] = Wkb; wa.dst[2] = Wvb; wa.dst[3] = Wob;
    prep_wcvt<<<dim3(512), 256, 0, stream>>>(wa);

    FusedArgs fa;
    // Q scale = 1/sqrt(64) * log2(e): scores land directly in log2 domain
    fa.s[0] = { query, Wqb, bq, Qp,  nullptr, 0.125f * LOG2E, 0 };
    fa.s[1] = { key,   Wkb, bk, Kp,  nullptr, 1.0f,   0 };
    fa.s[2] = { value, Wvb, bv, Vtp, nullptr, 1.0f,   2 };   // V stored transposed per head
    fa.mask = mask; fa.bits = bits;
    gemm_qkv_pack<<<dim3(GEMM_BLOCKS + PACK_BLOCKS), 256, 0, stream>>>(fa);

    attn_fwd<<<dim3(512), 256, 0, stream>>>(Qp, Kp, Vtp, bits, Xp);

    Gemm3 go;
    go.s[0] = { Xp, Wob, bo, nullptr, (float*)d_out, 1.0f, 3 };
    go.s[1] = go.s[0]; go.s[2] = go.s[0];
    gemm_o<<<dim3(128, 4), 256, 0, stream>>>(go);
}

// Round 15
// 135.589 us; speedup vs baseline: 1.0491x; 1.0491x over previous
//
#include <hip/hip_runtime.h>
#include <hip/hip_bf16.h>

#define DMODEL 512
#define NHEAD  8
#define DKH    64
#define SEQ    2048
#define NB     4
#define LOG2E  1.44269504088896f

typedef float f32x4 __attribute__((ext_vector_type(4)));
typedef float f32x16 __attribute__((ext_vector_type(16)));
typedef short bf16x8 __attribute__((ext_vector_type(8)));

__device__ __forceinline__ unsigned short f2bf(float x) {
    unsigned int u = __float_as_uint(x);
    u += 0x7fffu + ((u >> 16) & 1u);
    return (unsigned short)(u >> 16);
}

__device__ __forceinline__ void gload16(const void* g, void* l) {
    __builtin_amdgcn_global_load_lds(
        (const __attribute__((address_space(1))) unsigned int*)g,
        (__attribute__((address_space(3))) unsigned int*)l, 16, 0, 0);
}

__device__ __forceinline__ unsigned int cvtpk(float lo, float hi) {
    // no builtin on gfx950 (learn_hip m240) — inline asm
    unsigned int r;
    asm("v_cvt_pk_bf16_f32 %0, %1, %2" : "=v"(r) : "v"(lo), "v"(hi));
    return r;
}

// ---------------------------------------------------------------------------
// prep: [W f32->bf16 cvt: 512 blocks] + [mask bit-pack: 1024 blocks].
// Q/K/V cvt removed — the QKV GEMM reg-stages f32 directly (saves ~72MB of
// HBM traffic). Round-14 lesson: fusing pack into the GEMM launch REGRESSES
// (−6.5us) — pack blocks displace gemm blocks and contend for HBM. Keep split.
// ---------------------------------------------------------------------------
#define CVT_BLOCKS  512
#define PACK_BLOCKS 1024
struct PrepArgs {
    const float* src[4]; unsigned short* dst[4];
    const unsigned char* mask; unsigned long long* bits;
};

__global__ __launch_bounds__(256) void prep(PrepArgs a)
{
    const int bx = blockIdx.x;
    if (bx < CVT_BLOCKS) {
        const int seg = bx >> 7, base = bx & 127;
        const int i = (base * 256 + threadIdx.x) * 8;
        const float* s = a.src[seg];
        const float4 v0 = *reinterpret_cast<const float4*>(s + i);
        const float4 v1 = *reinterpret_cast<const float4*>(s + i + 4);
        ushort4 h0, h1;
        h0.x = f2bf(v0.x); h0.y = f2bf(v0.y); h0.z = f2bf(v0.z); h0.w = f2bf(v0.w);
        h1.x = f2bf(v1.x); h1.y = f2bf(v1.y); h1.z = f2bf(v1.z); h1.w = f2bf(v1.w);
        *reinterpret_cast<ushort4*>(a.dst[seg] + i)     = h0;
        *reinterpret_cast<ushort4*>(a.dst[seg] + i + 4) = h1;
    } else {
        __shared__ int anyb;
        if (threadIdx.x == 0) anyb = 0;
        __syncthreads();
        const uint4 dv = *reinterpret_cast<const uint4*>(a.mask + threadIdx.x * 16);
        if ((dv.x | dv.y | dv.z | dv.w) & 0xFFFFFF00u) atomicOr(&anyb, 1);
        __syncthreads();
        const int bytemode = anyb;

        const int w = (bx - CVT_BLOCKS) * 256 + threadIdx.x;   // 0..262143
        const int b = w >> 16, kt = (w >> 11) & 31, row = w & 2047;
        const size_t eoff = ((size_t)(b * SEQ + row)) * SEQ + kt * 64;
        unsigned long long word = 0;
        if (bytemode) {
            const unsigned char* mp = a.mask + eoff;
            #pragma unroll
            for (int c = 0; c < 4; ++c) {
                const uint4 v = *reinterpret_cast<const uint4*>(mp + c * 16);
                const unsigned int n0 = (v.x | (v.x >> 7) | (v.x >> 14) | (v.x >> 21)) & 0xFu;
                const unsigned int n1 = (v.y | (v.y >> 7) | (v.y >> 14) | (v.y >> 21)) & 0xFu;
                const unsigned int n2 = (v.z | (v.z >> 7) | (v.z >> 14) | (v.z >> 21)) & 0xFu;
                const unsigned int n3 = (v.w | (v.w >> 7) | (v.w >> 14) | (v.w >> 21)) & 0xFu;
                const unsigned int ch = n0 | (n1 << 4) | (n2 << 8) | (n3 << 12);
                word |= (unsigned long long)ch << (16 * c);
            }
        } else {
            const unsigned int* mp = (const unsigned int*)a.mask + eoff;
            #pragma unroll
            for (int c = 0; c < 16; ++c) {
                const uint4 v = *reinterpret_cast<const uint4*>(mp + c * 4);
                const unsigned int nb = (v.x | (v.y << 1) | (v.z << 2) | (v.w << 3)) & 0xFu;
                word |= (unsigned long long)nb << (4 * c);
            }
        }
        a.bits[w] = word;
    }
}

// ---------------------------------------------------------------------------
// bf16 GEMM template. AF32=true (BM=128 only): A is f32, reg-staged with
// in-kernel v_cvt_pk_bf16_f32 + swizzled ds_write_b128. Staging invariant
// matches the gload16 path: LDS[row, unit w^(row&7)] = A[row, unit w].
// Next tile's f32 loads prefetched under compute (T14). AF32=false: proven
// gload16 path unchanged.
// ---------------------------------------------------------------------------
struct GemmSet {
    const void* A; const unsigned short* W; const float* bias;
    unsigned short* outb; float* outf; float scale; int mode;
};
struct Gemm3 { GemmSet s[3]; };

template<int BM, bool AF32>
__global__ __launch_bounds__(256) void gemm_bf16(Gemm3 G)
{
    constexpr int NJ = (BM == 128) ? 4 : 2;
    __shared__ unsigned short As[BM * 64];
    __shared__ unsigned short Bs[128 * 64];

    const GemmSet gs = G.s[blockIdx.z];
    const int tid = threadIdx.x, lane = tid & 63, wv = tid >> 6;
    const int g = lane >> 4, lr = lane & 15;
    const int bm = blockIdx.x * BM, bn = blockIdx.y * 128;
    const int wm = (BM == 128) ? (wv & 1) * 64 : 0;
    const int wn = (BM == 128) ? (wv >> 1) * 64 : wv * 32;
    const int srow = lane >> 3;
    const int scol = 8 * ((lane & 7) ^ srow);

    // AF32 staging geometry: thread -> (row, 64-f32 half), 4x 16B units
    const int arow  = tid >> 1;      // 0..127
    const int ahalf = tid & 1;       // 0..1

    f32x4 acc[4][NJ] = {};
    float4 ra[8];

    if constexpr (AF32) {
        const float* Af = (const float*)gs.A;
        #pragma unroll
        for (int j = 0; j < 4; ++j) {
            const size_t gb = (size_t)(bm + arow) * DMODEL + ahalf * 32 + j * 8;
            ra[2*j]   = *reinterpret_cast<const float4*>(&Af[gb]);
            ra[2*j+1] = *reinterpret_cast<const float4*>(&Af[gb + 4]);
        }
    }

    #pragma unroll
    for (int kt = 0; kt < DMODEL; kt += 64) {
        __syncthreads();
        if constexpr (AF32) {
            #pragma unroll
            for (int j = 0; j < 4; ++j) {
                unsigned int w0 = cvtpk(ra[2*j].x,   ra[2*j].y);
                unsigned int w1 = cvtpk(ra[2*j].z,   ra[2*j].w);
                unsigned int w2 = cvtpk(ra[2*j+1].x, ra[2*j+1].y);
                unsigned int w3 = cvtpk(ra[2*j+1].z, ra[2*j+1].w);
                uint4 pkd; pkd.x = w0; pkd.y = w1; pkd.z = w2; pkd.w = w3;
                const int boff = (arow * 128 + ahalf * 64 + j * 16) ^ ((arow & 7) << 4);
                *reinterpret_cast<uint4*>((char*)As + boff) = pkd;   // ds_write_b128
            }
        } else {
            #pragma unroll
            for (int i = 0; i < BM / 32; ++i) {
                const int ch = i * 4 + wv;
                const int row = ch * 8 + srow;
                gload16(&((const unsigned short*)gs.A)[(size_t)(bm + row) * DMODEL + kt + scol],
                        &As[ch * 512 + lane * 8]);
            }
        }
        #pragma unroll
        for (int i = 0; i < 4; ++i) {
            const int ch = i * 4 + wv;
            const int row = ch * 8 + srow;
            gload16(&gs.W[(size_t)(bn + row) * DMODEL + kt + scol], &Bs[ch * 512 + lane * 8]);
        }
        if constexpr (AF32) {
            if (kt + 64 < DMODEL) {
                const float* Af = (const float*)gs.A;
                #pragma unroll
                for (int j = 0; j < 4; ++j) {
                    const size_t gb = (size_t)(bm + arow) * DMODEL + kt + 64 + ahalf * 32 + j * 8;
                    ra[2*j]   = *reinterpret_cast<const float4*>(&Af[gb]);
                    ra[2*j+1] = *reinterpret_cast<const float4*>(&Af[gb + 4]);
                }
            }
        }
        __syncthreads();

        #pragma unroll
        for (int kk = 0; kk < 2; ++kk) {
            bf16x8 af[4], bfr[NJ];
            #pragma unroll
            for (int x = 0; x < 4; ++x) {
                const int ra_ = wm + x * 16 + lr;
                af[x] = *reinterpret_cast<const bf16x8*>(
                    (const char*)As + ((ra_ * 128 + kk * 64 + g * 16) ^ ((ra_ & 7) << 4)));
            }
            #pragma unroll
            for (int y = 0; y < NJ; ++y) {
                const int rb = wn + y * 16 + lr;
                bfr[y] = *reinterpret_cast<const bf16x8*>(
                    (const char*)Bs + ((rb * 128 + kk * 64 + g * 16) ^ ((rb & 7) << 4)));
            }
            __builtin_amdgcn_s_setprio(1);
            #pragma unroll
            for (int mi = 0; mi < 4; ++mi)
                #pragma unroll
                for (int nj = 0; nj < NJ; ++nj)
                    acc[mi][nj] = __builtin_amdgcn_mfma_f32_16x16x32_bf16(af[mi], bfr[nj], acc[mi][nj], 0, 0, 0);
            __builtin_amdgcn_s_setprio(0);
        }
    }

    const int mode = gs.mode;
    #pragma unroll
    for (int mi = 0; mi < 4; ++mi) {
        #pragma unroll
        for (int nj = 0; nj < NJ; ++nj) {
            const int col  = bn + wn + nj * 16 + lr;
            const int row0 = bm + wm + mi * 16 + g * 4;
            const float bv = gs.bias[col];
            if (mode == 2) {
                const int bb = row0 >> 11, ss = row0 & (SEQ - 1);
                const int hh = col >> 6,  dd = col & 63;
                ushort4 pk;
                pk.x = f2bf(acc[mi][nj][0] + bv);
                pk.y = f2bf(acc[mi][nj][1] + bv);
                pk.z = f2bf(acc[mi][nj][2] + bv);
                pk.w = f2bf(acc[mi][nj][3] + bv);
                *reinterpret_cast<ushort4*>(&gs.outb[((size_t)((bb * NHEAD + hh) * DKH + dd)) * SEQ + ss]) = pk;
            } else if (mode == 3) {
                #pragma unroll
                for (int r = 0; r < 4; ++r)
                    gs.outf[(size_t)(row0 + r) * DMODEL + col] = acc[mi][nj][r] + bv;
            } else {
                #pragma unroll
                for (int r = 0; r < 4; ++r)
                    gs.outb[(size_t)(row0 + r) * DMODEL + col] = f2bf((acc[mi][nj][r] + bv) * gs.scale);
            }
        }
    }
}

// ---------------------------------------------------------------------------
// Flash attention — proven round-13 kernel (4 waves, KVBLK=128, counted-vmcnt
// raw barriers, 2-deep prefetch, exp2f [__builtin_amdgcn_exp2f is BANNED —
// failed rounds 7 & 12 with absmax ~0.74]).
// ---------------------------------------------------------------------------
__global__ __launch_bounds__(256) void attn_fwd(
    const unsigned short* __restrict__ Q,
    const unsigned short* __restrict__ K,
    const unsigned short* __restrict__ Vt,
    const unsigned long long* __restrict__ bits,
    unsigned short* __restrict__ X)
{
    __shared__ unsigned short Ks[2][2][64 * 64];   // [buf][half][64 rows x 128B]
    __shared__ unsigned short Vs[2][2][64 * 64];

    const int tid = threadIdx.x, lane = tid & 63, wv = tid >> 6;
    const int lr32 = lane & 31, hi = lane >> 5;
    const int bid = blockIdx.x;
    const int wg  = (bid & 7) * 64 + (bid >> 3);
    const int qb = wg & 15, h = (wg >> 4) & 7, b = wg >> 7;
    const int q0 = qb * 128, qw = q0 + wv * 32;

    const unsigned short* Kbh = K  + (size_t)b * SEQ * DMODEL + h * DKH;
    const unsigned short* Vbh = Vt + (size_t)(b * NHEAD + h) * DKH * SEQ;
    const unsigned long long* bitsb = bits + (size_t)b * 32 * SEQ + qw + lr32;

    bf16x8 qf[4];
    #pragma unroll
    for (int kd = 0; kd < 4; ++kd)
        qf[kd] = *reinterpret_cast<const bf16x8*>(
            &Q[(size_t)(b * SEQ + qw + lr32) * DMODEL + h * DKH + kd * 16 + hi * 8]);

    const int srow = lane >> 3;
    const int scol = 8 * ((lane & 7) ^ srow);

    auto stage = [&](int buf, int c) {
        #pragma unroll
        for (int i = 0; i < 4; ++i) {
            const int ch   = i * 4 + wv;
            const int half = ch >> 3;
            const int chh  = ch & 7;
            const int row  = chh * 8 + srow;
            const int kt   = c * 128 + half * 64;
            gload16(&Kbh[(size_t)(kt + row) * DMODEL + scol], &Ks[buf][half][chh * 512 + lane * 8]);
            gload16(&Vbh[(size_t)row * SEQ + kt + scol],      &Vs[buf][half][chh * 512 + lane * 8]);
        }
    };

    union { unsigned int u[4]; bf16x8 v; } onesu;
    onesu.u[0] = onesu.u[1] = onesu.u[2] = onesu.u[3] = 0x3F803F80u;
    const bf16x8 ones = onesu.v;

    f32x16 o0 = {}, o1 = {}, o_sum = {};

    stage(0, 0);
    stage(1, 1);   // 2-deep prefetch

    for (int t = 0; t < 16; ++t) {
        const int cur = t & 1;

        if (t < 15) asm volatile("s_waitcnt vmcnt(8)" ::: "memory");
        else        asm volatile("s_waitcnt vmcnt(0)" ::: "memory");
        __builtin_amdgcn_sched_barrier(0);
        __builtin_amdgcn_s_barrier();

        const unsigned long long mwA = bitsb[(size_t)(2 * t)     * SEQ];
        const unsigned long long mwB = bitsb[(size_t)(2 * t + 1) * SEQ];

        f32x16 sA0 = {}, sA1 = {}, sB0 = {}, sB1 = {};
        __builtin_amdgcn_s_setprio(1);
        #pragma unroll
        for (int kd = 0; kd < 4; ++kd) {
            const int cb = kd * 32 + hi * 16;
            const int r0 = lr32, r1 = 32 + lr32;
            const bf16x8 kfA0 = *reinterpret_cast<const bf16x8*>(
                (const char*)Ks[cur][0] + ((r0 * 128 + cb) ^ ((r0 & 7) << 4)));
            const bf16x8 kfA1 = *reinterpret_cast<const bf16x8*>(
                (const char*)Ks[cur][0] + ((r1 * 128 + cb) ^ ((r1 & 7) << 4)));
            const bf16x8 kfB0 = *reinterpret_cast<const bf16x8*>(
                (const char*)Ks[cur][1] + ((r0 * 128 + cb) ^ ((r0 & 7) << 4)));
            const bf16x8 kfB1 = *reinterpret_cast<const bf16x8*>(
                (const char*)Ks[cur][1] + ((r1 * 128 + cb) ^ ((r1 & 7) << 4)));
            sA0 = __builtin_amdgcn_mfma_f32_32x32x16_bf16(kfA0, qf[kd], sA0, 0, 0, 0);
            sA1 = __builtin_amdgcn_mfma_f32_32x32x16_bf16(kfA1, qf[kd], sA1, 0, 0, 0);
            sB0 = __builtin_amdgcn_mfma_f32_32x32x16_bf16(kfB0, qf[kd], sB0, 0, 0, 0);
            sB1 = __builtin_amdgcn_mfma_f32_32x32x16_bf16(kfB1, qf[kd], sB1, 0, 0, 0);
        }
        __builtin_amdgcn_s_setprio(0);

        auto subtile = [&](const f32x16& s0, const f32x16& s1,
                           unsigned long long mw, int sub) {
            const unsigned long long msh = mw >> (4 * hi);
            const unsigned int mlo = (unsigned int)msh;
            const unsigned int mhi = (unsigned int)(msh >> 32);
            unsigned int pk[8][2];
            #pragma unroll
            for (int kj = 0; kj < 2; ++kj) {
                const unsigned int msel = kj ? mhi : mlo;
                #pragma unroll
                for (int o2 = 0; o2 < 4; ++o2) {
                    float p[4];
                    #pragma unroll
                    for (int r = 0; r < 4; ++r) {
                        const int bitp = o2 * 8 + r;
                        const float mf = (float)(msel & (1u << bitp));    // 0 or 2^bitp exact
                        const float coef = -1024.f / (float)(1u << bitp); // exact
                        const float sv = kj ? s1[o2 * 4 + r] : s0[o2 * 4 + r];
                        p[r] = exp2f(__builtin_fmaf(mf, coef, sv));       // masked: exp2(s-1024)=0
                    }
                    pk[kj * 4 + o2][0] = cvtpk(p[0], p[1]);
                    pk[kj * 4 + o2][1] = cvtpk(p[2], p[3]);
                }
            }
            #pragma unroll
            for (int kk = 0; kk < 4; ++kk) {
                unsigned int a0 = pk[2 * kk][0], b0 = pk[2 * kk + 1][0];
                unsigned int a1 = pk[2 * kk][1], b1 = pk[2 * kk + 1][1];
                asm("v_permlane32_swap_b32 %0, %1" : "+v"(a0), "+v"(b0));
                asm("v_permlane32_swap_b32 %0, %1" : "+v"(a1), "+v"(b1));
                union { unsigned int u[4]; bf16x8 v; } fr;
                fr.u[0] = a0; fr.u[1] = a1; fr.u[2] = b0; fr.u[3] = b1;
                const int cb = kk * 32 + hi * 16;
                const int d0 = lr32, d1 = 32 + lr32;
                const bf16x8 vf0 = *reinterpret_cast<const bf16x8*>(
                    (const char*)Vs[cur][sub] + ((d0 * 128 + cb) ^ ((d0 & 7) << 4)));
                const bf16x8 vf1 = *reinterpret_cast<const bf16x8*>(
                    (const char*)Vs[cur][sub] + ((d1 * 128 + cb) ^ ((d1 & 7) << 4)));
                __builtin_amdgcn_s_setprio(1);
                o0    = __builtin_amdgcn_mfma_f32_32x32x16_bf16(fr.v, vf0, o0, 0, 0, 0);
                o1    = __builtin_amdgcn_mfma_f32_32x32x16_bf16(fr.v, vf1, o1, 0, 0, 0);
                o_sum = __builtin_amdgcn_mfma_f32_32x32x16_bf16(fr.v, ones, o_sum, 0, 0, 0);
                __builtin_amdgcn_s_setprio(0);
            }
        };
        subtile(sA0, sA1, mwA, 0);
        subtile(sB0, sB1, mwB, 1);

        __builtin_amdgcn_s_barrier();
        if (t + 2 <= 15) stage(cur, t + 2);
    }

    #pragma unroll
    for (int r = 0; r < 16; ++r) {
        const int qr = (r & 3) + 8 * (r >> 2) + 4 * hi;
        const float rv = 1.f / o_sum[r];
        const size_t rowoff = (size_t)(b * SEQ + qw + qr) * DMODEL + h * DKH + lr32;
        X[rowoff]      = f2bf(o0[r] * rv);
        X[rowoff + 32] = f2bf(o1[r] * rv);
    }
}

extern "C" void kernel_launch(void* const* d_in, const int* in_sizes, int n_in,
                              void* d_out, int out_size, void* d_ws, size_t ws_size,
                              hipStream_t stream)
{
    const float* query = (const float*)d_in[0];
    const float* key   = (const float*)d_in[1];
    const float* value = (const float*)d_in[2];
    const unsigned char* mask = (const unsigned char*)d_in[3];
    const float* Wq = (const float*)d_in[4];
    const float* bq = (const float*)d_in[5];
    const float* Wk = (const float*)d_in[6];
    const float* bk = (const float*)d_in[7];
    const float* Wv = (const float*)d_in[8];
    const float* bv = (const float*)d_in[9];
    const float* Wo = (const float*)d_in[10];
    const float* bo = (const float*)d_in[11];

    const size_t E = (size_t)(NB * SEQ) * DMODEL;          // 4,194,304
    const size_t WE = (size_t)DMODEL * DMODEL;             // 262,144
    unsigned short* Xp  = (unsigned short*)d_ws;
    unsigned short* Qp  = Xp + E;
    unsigned short* Kp  = Qp + E;
    unsigned short* Vtp = Kp + E;
    unsigned short* Wqb = Vtp + E;
    unsigned short* Wkb = Wqb + WE;
    unsigned short* Wvb = Wkb + WE;
    unsigned short* Wob = Wvb + WE;
    unsigned long long* bits = (unsigned long long*)(Wob + WE);

    PrepArgs pa;
    pa.src[0] = Wq; pa.src[1] = Wk; pa.src[2] = Wv; pa.src[3] = Wo;
    pa.dst[0] = Wqb; pa.dst[1] = Wkb; pa.dst[2] = Wvb; pa.dst[3] = Wob;
    pa.mask = mask; pa.bits = bits;
    prep<<<dim3(CVT_BLOCKS + PACK_BLOCKS), 256, 0, stream>>>(pa);

    Gemm3 gq;
    // Q scale = 1/sqrt(64) * log2(e): scores land directly in log2 domain
    gq.s[0] = { query, Wqb, bq, Qp,  nullptr, 0.125f * LOG2E, 0 };
    gq.s[1] = { key,   Wkb, bk, Kp,  nullptr, 1.0f,   0 };
    gq.s[2] = { value, Wvb, bv, Vtp, nullptr, 1.0f,   2 };   // V stored transposed per head
    gemm_bf16<128, true><<<dim3(64, 4, 3), 256, 0, stream>>>(gq);

    attn_fwd<<<dim3(512), 256, 0, stream>>>(Qp, Kp, Vtp, bits, Xp);

    Gemm3 go;
    go.s[0] = { Xp, Wob, bo, nullptr, (float*)d_out, 1.0f, 3 };
    go.s[1] = go.s[0]; go.s[2] = go.s[0];
    gemm_bf16<64, false><<<dim3(128, 4, 1), 256, 0, stream>>>(go);
}

// Round 16
// 132.849 us; speedup vs baseline: 1.0707x; 1.0206x over previous
//
#include <hip/hip_runtime.h>
#include <hip/hip_bf16.h>

#define DMODEL 512
#define NHEAD  8
#define DKH    64
#define SEQ    2048
#define NB     4
#define LOG2E  1.44269504088896f

typedef float f32x4 __attribute__((ext_vector_type(4)));
typedef float f32x16 __attribute__((ext_vector_type(16)));
typedef short bf16x8 __attribute__((ext_vector_type(8)));

__device__ __forceinline__ unsigned short f2bf(float x) {
    unsigned int u = __float_as_uint(x);
    u += 0x7fffu + ((u >> 16) & 1u);
    return (unsigned short)(u >> 16);
}

__device__ __forceinline__ void gload16(const void* g, void* l) {
    __builtin_amdgcn_global_load_lds(
        (const __attribute__((address_space(1))) unsigned int*)g,
        (__attribute__((address_space(3))) unsigned int*)l, 16, 0, 0);
}

__device__ __forceinline__ unsigned int cvtpk(float lo, float hi) {
    // no builtin on gfx950 (learn_hip m240) — inline asm
    unsigned int r;
    asm("v_cvt_pk_bf16_f32 %0, %1, %2" : "=v"(r) : "v"(lo), "v"(hi));
    return r;
}

// ---------------------------------------------------------------------------
// prep: [W f32->bf16 cvt: 512 blocks] + [mask bit-pack: 1024 blocks].
// Round-14 lesson: fusing pack into the GEMM launch REGRESSES — keep split.
// ---------------------------------------------------------------------------
#define CVT_BLOCKS  512
#define PACK_BLOCKS 1024
struct PrepArgs {
    const float* src[4]; unsigned short* dst[4];
    const unsigned char* mask; unsigned long long* bits;
};

__global__ __launch_bounds__(256) void prep(PrepArgs a)
{
    const int bx = blockIdx.x;
    if (bx < CVT_BLOCKS) {
        const int seg = bx >> 7, base = bx & 127;
        const int i = (base * 256 + threadIdx.x) * 8;
        const float* s = a.src[seg];
        const float4 v0 = *reinterpret_cast<const float4*>(s + i);
        const float4 v1 = *reinterpret_cast<const float4*>(s + i + 4);
        ushort4 h0, h1;
        h0.x = f2bf(v0.x); h0.y = f2bf(v0.y); h0.z = f2bf(v0.z); h0.w = f2bf(v0.w);
        h1.x = f2bf(v1.x); h1.y = f2bf(v1.y); h1.z = f2bf(v1.z); h1.w = f2bf(v1.w);
        *reinterpret_cast<ushort4*>(a.dst[seg] + i)     = h0;
        *reinterpret_cast<ushort4*>(a.dst[seg] + i + 4) = h1;
    } else {
        __shared__ int anyb;
        if (threadIdx.x == 0) anyb = 0;
        __syncthreads();
        const uint4 dv = *reinterpret_cast<const uint4*>(a.mask + threadIdx.x * 16);
        if ((dv.x | dv.y | dv.z | dv.w) & 0xFFFFFF00u) atomicOr(&anyb, 1);
        __syncthreads();
        const int bytemode = anyb;

        const int w = (bx - CVT_BLOCKS) * 256 + threadIdx.x;   // 0..262143
        const int b = w >> 16, kt = (w >> 11) & 31, row = w & 2047;
        const size_t eoff = ((size_t)(b * SEQ + row)) * SEQ + kt * 64;
        unsigned long long word = 0;
        if (bytemode) {
            const unsigned char* mp = a.mask + eoff;
            #pragma unroll
            for (int c = 0; c < 4; ++c) {
                const uint4 v = *reinterpret_cast<const uint4*>(mp + c * 16);
                const unsigned int n0 = (v.x | (v.x >> 7) | (v.x >> 14) | (v.x >> 21)) & 0xFu;
                const unsigned int n1 = (v.y | (v.y >> 7) | (v.y >> 14) | (v.y >> 21)) & 0xFu;
                const unsigned int n2 = (v.z | (v.z >> 7) | (v.z >> 14) | (v.z >> 21)) & 0xFu;
                const unsigned int n3 = (v.w | (v.w >> 7) | (v.w >> 14) | (v.w >> 21)) & 0xFu;
                const unsigned int ch = n0 | (n1 << 4) | (n2 << 8) | (n3 << 12);
                word |= (unsigned long long)ch << (16 * c);
            }
        } else {
            const unsigned int* mp = (const unsigned int*)a.mask + eoff;
            #pragma unroll
            for (int c = 0; c < 16; ++c) {
                const uint4 v = *reinterpret_cast<const uint4*>(mp + c * 4);
                const unsigned int nb = (v.x | (v.y << 1) | (v.z << 2) | (v.w << 3)) & 0xFu;
                word |= (unsigned long long)nb << (4 * c);
            }
        }
        a.bits[w] = word;
    }
}

// ---------------------------------------------------------------------------
// bf16 GEMM template. AF32=true (BM=128 only): A is f32, reg-staged with
// v_cvt_pk_bf16_f32 + swizzled ds_write_b128 (invariant matches gload16
// path); next tile's f32 loads prefetched under compute.
// ---------------------------------------------------------------------------
struct GemmSet {
    const void* A; const unsigned short* W; const float* bias;
    unsigned short* outb; float* outf; float scale; int mode;
};
struct Gemm3 { GemmSet s[3]; };

template<int BM, bool AF32>
__global__ __launch_bounds__(256) void gemm_bf16(Gemm3 G)
{
    constexpr int NJ = (BM == 128) ? 4 : 2;
    __shared__ unsigned short As[BM * 64];
    __shared__ unsigned short Bs[128 * 64];

    const GemmSet gs = G.s[blockIdx.z];
    const int tid = threadIdx.x, lane = tid & 63, wv = tid >> 6;
    const int g = lane >> 4, lr = lane & 15;
    const int bm = blockIdx.x * BM, bn = blockIdx.y * 128;
    const int wm = (BM == 128) ? (wv & 1) * 64 : 0;
    const int wn = (BM == 128) ? (wv >> 1) * 64 : wv * 32;
    const int srow = lane >> 3;
    const int scol = 8 * ((lane & 7) ^ srow);

    const int arow  = tid >> 1;      // 0..127
    const int ahalf = tid & 1;       // 0..1

    f32x4 acc[4][NJ] = {};
    float4 ra[8];

    if constexpr (AF32) {
        const float* Af = (const float*)gs.A;
        #pragma unroll
        for (int j = 0; j < 4; ++j) {
            const size_t gb = (size_t)(bm + arow) * DMODEL + ahalf * 32 + j * 8;
            ra[2*j]   = *reinterpret_cast<const float4*>(&Af[gb]);
            ra[2*j+1] = *reinterpret_cast<const float4*>(&Af[gb + 4]);
        }
    }

    #pragma unroll
    for (int kt = 0; kt < DMODEL; kt += 64) {
        __syncthreads();
        if constexpr (AF32) {
            #pragma unroll
            for (int j = 0; j < 4; ++j) {
                unsigned int w0 = cvtpk(ra[2*j].x,   ra[2*j].y);
                unsigned int w1 = cvtpk(ra[2*j].z,   ra[2*j].w);
                unsigned int w2 = cvtpk(ra[2*j+1].x, ra[2*j+1].y);
                unsigned int w3 = cvtpk(ra[2*j+1].z, ra[2*j+1].w);
                uint4 pkd; pkd.x = w0; pkd.y = w1; pkd.z = w2; pkd.w = w3;
                const int boff = (arow * 128 + ahalf * 64 + j * 16) ^ ((arow & 7) << 4);
                *reinterpret_cast<uint4*>((char*)As + boff) = pkd;   // ds_write_b128
            }
        } else {
            #pragma unroll
            for (int i = 0; i < BM / 32; ++i) {
                const int ch = i * 4 + wv;
                const int row = ch * 8 + srow;
                gload16(&((const unsigned short*)gs.A)[(size_t)(bm + row) * DMODEL + kt + scol],
                        &As[ch * 512 + lane * 8]);
            }
        }
        #pragma unroll
        for (int i = 0; i < 4; ++i) {
            const int ch = i * 4 + wv;
            const int row = ch * 8 + srow;
            gload16(&gs.W[(size_t)(bn + row) * DMODEL + kt + scol], &Bs[ch * 512 + lane * 8]);
        }
        if constexpr (AF32) {
            if (kt + 64 < DMODEL) {
                const float* Af = (const float*)gs.A;
                #pragma unroll
                for (int j = 0; j < 4; ++j) {
                    const size_t gb = (size_t)(bm + arow) * DMODEL + kt + 64 + ahalf * 32 + j * 8;
                    ra[2*j]   = *reinterpret_cast<const float4*>(&Af[gb]);
                    ra[2*j+1] = *reinterpret_cast<const float4*>(&Af[gb + 4]);
                }
            }
        }
        __syncthreads();

        #pragma unroll
        for (int kk = 0; kk < 2; ++kk) {
            bf16x8 af[4], bfr[NJ];
            #pragma unroll
            for (int x = 0; x < 4; ++x) {
                const int ra_ = wm + x * 16 + lr;
                af[x] = *reinterpret_cast<const bf16x8*>(
                    (const char*)As + ((ra_ * 128 + kk * 64 + g * 16) ^ ((ra_ & 7) << 4)));
            }
            #pragma unroll
            for (int y = 0; y < NJ; ++y) {
                const int rb = wn + y * 16 + lr;
                bfr[y] = *reinterpret_cast<const bf16x8*>(
                    (const char*)Bs + ((rb * 128 + kk * 64 + g * 16) ^ ((rb & 7) << 4)));
            }
            __builtin_amdgcn_s_setprio(1);
            #pragma unroll
            for (int mi = 0; mi < 4; ++mi)
                #pragma unroll
                for (int nj = 0; nj < NJ; ++nj)
                    acc[mi][nj] = __builtin_amdgcn_mfma_f32_16x16x32_bf16(af[mi], bfr[nj], acc[mi][nj], 0, 0, 0);
            __builtin_amdgcn_s_setprio(0);
        }
    }

    const int mode = gs.mode;
    #pragma unroll
    for (int mi = 0; mi < 4; ++mi) {
        #pragma unroll
        for (int nj = 0; nj < NJ; ++nj) {
            const int col  = bn + wn + nj * 16 + lr;
            const int row0 = bm + wm + mi * 16 + g * 4;
            const float bv = gs.bias[col];
            if (mode == 2) {
                const int bb = row0 >> 11, ss = row0 & (SEQ - 1);
                const int hh = col >> 6,  dd = col & 63;
                ushort4 pk;
                pk.x = f2bf(acc[mi][nj][0] + bv);
                pk.y = f2bf(acc[mi][nj][1] + bv);
                pk.z = f2bf(acc[mi][nj][2] + bv);
                pk.w = f2bf(acc[mi][nj][3] + bv);
                *reinterpret_cast<ushort4*>(&gs.outb[((size_t)((bb * NHEAD + hh) * DKH + dd)) * SEQ + ss]) = pk;
            } else if (mode == 3) {
                #pragma unroll
                for (int r = 0; r < 4; ++r)
                    gs.outf[(size_t)(row0 + r) * DMODEL + col] = acc[mi][nj][r] + bv;
            } else {
                #pragma unroll
                for (int r = 0; r < 4; ++r)
                    gs.outb[(size_t)(row0 + r) * DMODEL + col] = f2bf((acc[mi][nj][r] + bv) * gs.scale);
            }
        }
    }
}

// ---------------------------------------------------------------------------
// Flash attention — round-13/15 structure; ONE change: packed-mask zeroing.
// Old: p = exp2f(fma(mf, coef, sv)) — 3 VALU/elem pre-exp.
// New: p = exp2f(sv) unconditionally (sv <= ~12, finite), then clear masked
// bf16 halfwords on the packed words: keep = sext(bit of ~msel) per elem
// (v_bfe_i32 idiom), v_perm halfword blend, v_and. 2 VALU/elem, shorter
// MFMA->exp chain. Masked halfword = 0x0000 = +0.0 exactly (same as before).
// exp2f proven; __builtin_amdgcn_exp2f BANNED (failed r7/r12).
// ---------------------------------------------------------------------------
__global__ __launch_bounds__(256) void attn_fwd(
    const unsigned short* __restrict__ Q,
    const unsigned short* __restrict__ K,
    const unsigned short* __restrict__ Vt,
    const unsigned long long* __restrict__ bits,
    unsigned short* __restrict__ X)
{
    __shared__ unsigned short Ks[2][2][64 * 64];   // [buf][half][64 rows x 128B]
    __shared__ unsigned short Vs[2][2][64 * 64];

    const int tid = threadIdx.x, lane = tid & 63, wv = tid >> 6;
    const int lr32 = lane & 31, hi = lane >> 5;
    const int bid = blockIdx.x;
    const int wg  = (bid & 7) * 64 + (bid >> 3);
    const int qb = wg & 15, h = (wg >> 4) & 7, b = wg >> 7;
    const int q0 = qb * 128, qw = q0 + wv * 32;

    const unsigned short* Kbh = K  + (size_t)b * SEQ * DMODEL + h * DKH;
    const unsigned short* Vbh = Vt + (size_t)(b * NHEAD + h) * DKH * SEQ;
    const unsigned long long* bitsb = bits + (size_t)b * 32 * SEQ + qw + lr32;

    bf16x8 qf[4];
    #pragma unroll
    for (int kd = 0; kd < 4; ++kd)
        qf[kd] = *reinterpret_cast<const bf16x8*>(
            &Q[(size_t)(b * SEQ + qw + lr32) * DMODEL + h * DKH + kd * 16 + hi * 8]);

    const int srow = lane >> 3;
    const int scol = 8 * ((lane & 7) ^ srow);

    auto stage = [&](int buf, int c) {
        #pragma unroll
        for (int i = 0; i < 4; ++i) {
            const int ch   = i * 4 + wv;
            const int half = ch >> 3;
            const int chh  = ch & 7;
            const int row  = chh * 8 + srow;
            const int kt   = c * 128 + half * 64;
            gload16(&Kbh[(size_t)(kt + row) * DMODEL + scol], &Ks[buf][half][chh * 512 + lane * 8]);
            gload16(&Vbh[(size_t)row * SEQ + kt + scol],      &Vs[buf][half][chh * 512 + lane * 8]);
        }
    };

    union { unsigned int u[4]; bf16x8 v; } onesu;
    onesu.u[0] = onesu.u[1] = onesu.u[2] = onesu.u[3] = 0x3F803F80u;
    const bf16x8 ones = onesu.v;

    f32x16 o0 = {}, o1 = {}, o_sum = {};

    stage(0, 0);
    stage(1, 1);   // 2-deep prefetch

    for (int t = 0; t < 16; ++t) {
        const int cur = t & 1;

        if (t < 15) asm volatile("s_waitcnt vmcnt(8)" ::: "memory");
        else        asm volatile("s_waitcnt vmcnt(0)" ::: "memory");
        __builtin_amdgcn_sched_barrier(0);
        __builtin_amdgcn_s_barrier();

        const unsigned long long mwA = bitsb[(size_t)(2 * t)     * SEQ];
        const unsigned long long mwB = bitsb[(size_t)(2 * t + 1) * SEQ];

        f32x16 sA0 = {}, sA1 = {}, sB0 = {}, sB1 = {};
        __builtin_amdgcn_s_setprio(1);
        #pragma unroll
        for (int kd = 0; kd < 4; ++kd) {
            const int cb = kd * 32 + hi * 16;
            const int r0 = lr32, r1 = 32 + lr32;
            const bf16x8 kfA0 = *reinterpret_cast<const bf16x8*>(
                (const char*)Ks[cur][0] + ((r0 * 128 + cb) ^ ((r0 & 7) << 4)));
            const bf16x8 kfA1 = *reinterpret_cast<const bf16x8*>(
                (const char*)Ks[cur][0] + ((r1 * 128 + cb) ^ ((r1 & 7) << 4)));
            const bf16x8 kfB0 = *reinterpret_cast<const bf16x8*>(
                (const char*)Ks[cur][1] + ((r0 * 128 + cb) ^ ((r0 & 7) << 4)));
            const bf16x8 kfB1 = *reinterpret_cast<const bf16x8*>(
                (const char*)Ks[cur][1] + ((r1 * 128 + cb) ^ ((r1 & 7) << 4)));
            sA0 = __builtin_amdgcn_mfma_f32_32x32x16_bf16(kfA0, qf[kd], sA0, 0, 0, 0);
            sA1 = __builtin_amdgcn_mfma_f32_32x32x16_bf16(kfA1, qf[kd], sA1, 0, 0, 0);
            sB0 = __builtin_amdgcn_mfma_f32_32x32x16_bf16(kfB0, qf[kd], sB0, 0, 0, 0);
            sB1 = __builtin_amdgcn_mfma_f32_32x32x16_bf16(kfB1, qf[kd], sB1, 0, 0, 0);
        }
        __builtin_amdgcn_s_setprio(0);

        auto subtile = [&](const f32x16& s0, const f32x16& s1,
                           unsigned long long mw, int sub) {
            const unsigned long long msh = mw >> (4 * hi);
            const unsigned int nlo = ~(unsigned int)msh;          // keep-bits
            const unsigned int nhi = ~(unsigned int)(msh >> 32);
            unsigned int pk[8][2];
            #pragma unroll
            for (int kj = 0; kj < 2; ++kj) {
                const unsigned int nsel = kj ? nhi : nlo;
                #pragma unroll
                for (int o2 = 0; o2 < 4; ++o2) {
                    const int b0 = o2 * 8;
                    float p[4];
                    #pragma unroll
                    for (int r = 0; r < 4; ++r) {
                        const float sv = kj ? s1[o2 * 4 + r] : s0[o2 * 4 + r];
                        p[r] = exp2f(sv);                          // sv <= ~12, finite
                    }
                    // keep-masks: 0xFFFFFFFF where unmasked (bit of nsel set)
                    const unsigned int k0 = (unsigned int)(((int)(nsel << (31 - b0)))       >> 31);
                    const unsigned int k1 = (unsigned int)(((int)(nsel << (31 - (b0 + 1)))) >> 31);
                    const unsigned int k2 = (unsigned int)(((int)(nsel << (31 - (b0 + 2)))) >> 31);
                    const unsigned int k3 = (unsigned int)(((int)(nsel << (31 - (b0 + 3)))) >> 31);
                    const unsigned int m01 = __builtin_amdgcn_perm(k1, k0, 0x05040100u);
                    const unsigned int m23 = __builtin_amdgcn_perm(k3, k2, 0x05040100u);
                    pk[kj * 4 + o2][0] = cvtpk(p[0], p[1]) & m01;
                    pk[kj * 4 + o2][1] = cvtpk(p[2], p[3]) & m23;
                }
            }
            #pragma unroll
            for (int kk = 0; kk < 4; ++kk) {
                unsigned int a0 = pk[2 * kk][0], b0 = pk[2 * kk + 1][0];
                unsigned int a1 = pk[2 * kk][1], b1 = pk[2 * kk + 1][1];
                asm("v_permlane32_swap_b32 %0, %1" : "+v"(a0), "+v"(b0));
                asm("v_permlane32_swap_b32 %0, %1" : "+v"(a1), "+v"(b1));
                union { unsigned int u[4]; bf16x8 v; } fr;
                fr.u[0] = a0; fr.u[1] = a1; fr.u[2] = b0; fr.u[3] = b1;
                const int cb = kk * 32 + hi * 16;
                const int d0 = lr32, d1 = 32 + lr32;
                const bf16x8 vf0 = *reinterpret_cast<const bf16x8*>(
                    (const char*)Vs[cur][sub] + ((d0 * 128 + cb) ^ ((d0 & 7) << 4)));
                const bf16x8 vf1 = *reinterpret_cast<const bf16x8*>(
                    (const char*)Vs[cur][sub] + ((d1 * 128 + cb) ^ ((d1 & 7) << 4)));
                __builtin_amdgcn_s_setprio(1);
                o0    = __builtin_amdgcn_mfma_f32_32x32x16_bf16(fr.v, vf0, o0, 0, 0, 0);
                o1    = __builtin_amdgcn_mfma_f32_32x32x16_bf16(fr.v, vf1, o1, 0, 0, 0);
                o_sum = __builtin_amdgcn_mfma_f32_32x32x16_bf16(fr.v, ones, o_sum, 0, 0, 0);
                __builtin_amdgcn_s_setprio(0);
            }
        };
        subtile(sA0, sA1, mwA, 0);
        subtile(sB0, sB1, mwB, 1);

        __builtin_amdgcn_s_barrier();
        if (t + 2 <= 15) stage(cur, t + 2);
    }

    #pragma unroll
    for (int r = 0; r < 16; ++r) {
        const int qr = (r & 3) + 8 * (r >> 2) + 4 * hi;
        const float rv = 1.f / o_sum[r];
        const size_t rowoff = (size_t)(b * SEQ + qw + qr) * DMODEL + h * DKH + lr32;
        X[rowoff]      = f2bf(o0[r] * rv);
        X[rowoff + 32] = f2bf(o1[r] * rv);
    }
}

extern "C" void kernel_launch(void* const* d_in, const int* in_sizes, int n_in,
                              void* d_out, int out_size, void* d_ws, size_t ws_size,
                              hipStream_t stream)
{
    const float* query = (const float*)d_in[0];
    const float* key   = (const float*)d_in[1];
    const float* value = (const float*)d_in[2];
    const unsigned char* mask = (const unsigned char*)d_in[3];
    const float* Wq = (const float*)d_in[4];
    const float* bq = (const float*)d_in[5];
    const float* Wk = (const float*)d_in[6];
    const float* bk = (const float*)d_in[7];
    const float* Wv = (const float*)d_in[8];
    const float* bv = (const float*)d_in[9];
    const float* Wo = (const float*)d_in[10];
    const float* bo = (const float*)d_in[11];

    const size_t E = (size_t)(NB * SEQ) * DMODEL;          // 4,194,304
    const size_t WE = (size_t)DMODEL * DMODEL;             // 262,144
    unsigned short* Xp  = (unsigned short*)d_ws;
    unsigned short* Qp  = Xp + E;
    unsigned short* Kp  = Qp + E;
    unsigned short* Vtp = Kp + E;
    unsigned short* Wqb = Vtp + E;
    unsigned short* Wkb = Wqb + WE;
    unsigned short* Wvb = Wkb + WE;
    unsigned short* Wob = Wvb + WE;
    unsigned long long* bits = (unsigned long long*)(Wob + WE);

    PrepArgs pa;
    pa.src[0] = Wq; pa.src[1] = Wk; pa.src[2] = Wv; pa.src[3] = Wo;
    pa.dst[0] = Wqb; pa.dst[1] = Wkb; pa.dst[2] = Wvb; pa.dst[3] = Wob;
    pa.mask = mask; pa.bits = bits;
    prep<<<dim3(CVT_BLOCKS + PACK_BLOCKS), 256, 0, stream>>>(pa);

    Gemm3 gq;
    // Q scale = 1/sqrt(64) * log2(e): scores land directly in log2 domain
    gq.s[0] = { query, Wqb, bq, Qp,  nullptr, 0.125f * LOG2E, 0 };
    gq.s[1] = { key,   Wkb, bk, Kp,  nullptr, 1.0f,   0 };
    gq.s[2] = { value, Wvb, bv, Vtp, nullptr, 1.0f,   2 };   // V stored transposed per head
    gemm_bf16<128, true><<<dim3(64, 4, 3), 256, 0, stream>>>(gq);

    attn_fwd<<<dim3(512), 256, 0, stream>>>(Qp, Kp, Vtp, bits, Xp);

    Gemm3 go;
    go.s[0] = { Xp, Wob, bo, nullptr, (float*)d_out, 1.0f, 3 };
    go.s[1] = go.s[0]; go.s[2] = go.s[0];
    gemm_bf16<64, false><<<dim3(128, 4, 1), 256, 0, stream>>>(go);
}